// Round 1
// baseline (363.920 us; speedup 1.0000x reference)
//
#include <hip/hip_runtime.h>
#include <math.h>

#define B_ 64
#define N_ 16384
#define D_ 64
#define K_ 8
#define SCALE 0.125f          // 1/sqrt(64)
#define LN_EPS 1e-5f
#define CHUNKS 16
#define ROWS_PER_CHUNK (N_ / CHUNKS)   // 1024
#define NT 256
#define TILES (ROWS_PER_CHUNK / NT)    // 4
#define REC 528                        // per-b qprep / per-(b,chunk) partial record: 512 Y + 8 S + 8 t1

__device__ __forceinline__ float wsum64(float v) {
#pragma unroll
  for (int m = 1; m < 64; m <<= 1) v += __shfl_xor(v, m);
  return v;
}

// slots = mu + sigma * noise   (32768 elems)
__global__ void init_slots(const float* __restrict__ noise, const float* __restrict__ mu,
                           const float* __restrict__ sg, float* __restrict__ slots) {
  int i = blockIdx.x * blockDim.x + threadIdx.x;
  int d = i & 63;
  slots[i] = mu[d] + sg[d] * noise[i];
}

// Per (b,kk): q = LN(slots; ln_slots)@wq + bq ; fold through wk and input-LN affine:
//   qp[c] = sum_d wk[c,d] q[d];  c0 = q . bk
//   qw[c] = qp[c]*ln_in_w[c]*SCALE ; As = sum qw ; Bc = (sum qp*ln_in_b + c0)*SCALE
__global__ __launch_bounds__(64) void prep_q(
    const float* __restrict__ slots,
    const float* __restrict__ lnsw, const float* __restrict__ lnsb,
    const float* __restrict__ wq, const float* __restrict__ bq,
    const float* __restrict__ wk, const float* __restrict__ bk,
    const float* __restrict__ lniw, const float* __restrict__ lnib,
    float* __restrict__ qprep) {
  const int bk_i = blockIdx.x;            // b*8+kk
  const int b = bk_i >> 3, kk = bk_i & 7;
  const int d = threadIdx.x;
  __shared__ float xs[64], qsh[64], wkl[64 * 65];
  // stage wk coalesced into padded LDS (read later as rows)
  for (int i = 0; i < 64; ++i) wkl[i * 65 + d] = wk[i * 64 + d];
  float s = slots[bk_i * 64 + d];
  float m = wsum64(s) * (1.f / 64.f);
  float df = s - m;
  float var = wsum64(df * df) * (1.f / 64.f);
  float r = 1.f / sqrtf(var + LN_EPS);
  xs[d] = df * r * lnsw[d] + lnsb[d];
  __syncthreads();
  float q = bq[d];
  for (int c = 0; c < 64; ++c) q += xs[c] * wq[c * 64 + d];
  qsh[d] = q;
  __syncthreads();
  float qp = 0.f, c0 = 0.f;
  for (int dd = 0; dd < 64; ++dd) {
    float qd = qsh[dd];
    qp += wkl[d * 65 + dd] * qd;
    c0 += qd * bk[dd];
  }
  float qw = qp * lniw[d] * SCALE;
  float As = wsum64(qw);
  float Bp = wsum64(qp * lnib[d]);
  float Bc = (Bp + c0) * SCALE;
  float* rec = qprep + b * REC;
  rec[d * 8 + kk] = qw;                   // qwT[c][kk]
  if (d == 0) { rec[512 + kk] = As; rec[520 + kk] = Bc; }
}

// Main streaming pass: grid = B*CHUNKS blocks x 256 threads.
// Each block: 4 tiles of 256 rows. Phase A: thread owns one row in registers
// (stats + 8 dots + softmax over slots). Phase B: transposed LDS tile,
// thread (kk-pair, d) accumulates Y[kk,d] over rows.
__global__ __launch_bounds__(256) void attn_pass(
    const float* __restrict__ inp, const float* __restrict__ qprep,
    float* __restrict__ part) {
  __shared__ float xT[64 * 129];          // transposed half-tile [c][n], pad 129
  __shared__ float awr[4 * 512];          // a*r pairs: [pair][n*2 + half]
  __shared__ float qwT[512];
  __shared__ float AsBc[16];
  __shared__ float redS[4 * 16];
  __shared__ float accST[16];             // S[0..7], t1[0..7] block accumulators
  const int tid = threadIdx.x;
  const int b = blockIdx.x >> 4, chunk = blockIdx.x & 15;
  for (int i = tid; i < 512; i += 256) qwT[i] = qprep[b * REC + i];
  if (tid < 16) { AsBc[tid] = qprep[b * REC + 512 + tid]; accST[tid] = 0.f; }
  __syncthreads();
  const int kk0 = (tid >> 6) * 2;         // wave w handles slots 2w, 2w+1
  const int dd = tid & 63;
  float Y0 = 0.f, Y1 = 0.f;
  const float* srcbase = inp + ((size_t)b * N_ + (size_t)chunk * ROWS_PER_CHUNK) * D_;
  for (int t = 0; t < TILES; ++t) {
    const float* src = srcbase + (size_t)(t * NT + tid) * D_;
    float4 x[16];
#pragma unroll
    for (int j = 0; j < 16; ++j) x[j] = reinterpret_cast<const float4*>(src)[j];
    float sum = 0.f, sq = 0.f;
    float l[8];
#pragma unroll
    for (int kk = 0; kk < 8; ++kk) l[kk] = 0.f;
#pragma unroll
    for (int j = 0; j < 16; ++j) {
      float xc[4] = {x[j].x, x[j].y, x[j].z, x[j].w};
#pragma unroll
      for (int e = 0; e < 4; ++e) {
        const int c = j * 4 + e;
        const float v = xc[e];
        sum += v; sq += v * v;
        const float4 qa = *reinterpret_cast<const float4*>(&qwT[c * 8]);
        const float4 qb = *reinterpret_cast<const float4*>(&qwT[c * 8 + 4]);
        l[0] += qa.x * v; l[1] += qa.y * v; l[2] += qa.z * v; l[3] += qa.w * v;
        l[4] += qb.x * v; l[5] += qb.y * v; l[6] += qb.z * v; l[7] += qb.w * v;
      }
    }
    const float m = sum * (1.f / 64.f);
    const float var = sq * (1.f / 64.f) - m * m;
    const float r = 1.f / sqrtf(var + LN_EPS);
    const float mr = m * r;
    float lmax = -1e30f;
#pragma unroll
    for (int kk = 0; kk < 8; ++kk) {
      l[kk] = r * l[kk] - mr * AsBc[kk] + AsBc[8 + kk];
      lmax = fmaxf(lmax, l[kk]);
    }
    float es = 0.f;
#pragma unroll
    for (int kk = 0; kk < 8; ++kk) { l[kk] = expf(l[kk] - lmax); es += l[kk]; }
    const float inv = 1.f / es;
#pragma unroll
    for (int kk = 0; kk < 8; ++kk) l[kk] *= inv;     // a[kk]
    // write a*r pairs (conflict-light b64 stores)
#pragma unroll
    for (int p = 0; p < 4; ++p) {
      float2 w2; w2.x = l[2 * p] * r; w2.y = l[2 * p + 1] * r;
      *reinterpret_cast<float2*>(&awr[p * 512 + tid * 2]) = w2;
    }
    // butterfly-reduce S (sum a) and t1 (sum a*m*r) per wave
    float red[16];
#pragma unroll
    for (int kk = 0; kk < 8; ++kk) {
      red[kk] = wsum64(l[kk]);
      red[8 + kk] = wsum64(l[kk] * mr);
    }
    if ((tid & 63) == 0) {
      const int w = tid >> 6;
#pragma unroll
      for (int i = 0; i < 16; ++i) redS[w * 16 + i] = red[i];
    }
    __syncthreads();
    if (tid < 16) accST[tid] += redS[tid] + redS[16 + tid] + redS[32 + tid] + redS[48 + tid];
    // stage half 1 (rows 0..127) transposed
    if (tid < 128) {
#pragma unroll
      for (int j = 0; j < 16; ++j) {
        xT[(j * 4 + 0) * 129 + tid] = x[j].x;
        xT[(j * 4 + 1) * 129 + tid] = x[j].y;
        xT[(j * 4 + 2) * 129 + tid] = x[j].z;
        xT[(j * 4 + 3) * 129 + tid] = x[j].w;
      }
    }
    __syncthreads();
#pragma unroll 8
    for (int n = 0; n < 128; ++n) {
      const float2 aw = *reinterpret_cast<const float2*>(&awr[(kk0 >> 1) * 512 + n * 2]);
      const float xv = xT[dd * 129 + n];
      Y0 += aw.x * xv; Y1 += aw.y * xv;
    }
    __syncthreads();
    if (tid >= 128) {
      const int tn = tid - 128;
#pragma unroll
      for (int j = 0; j < 16; ++j) {
        xT[(j * 4 + 0) * 129 + tn] = x[j].x;
        xT[(j * 4 + 1) * 129 + tn] = x[j].y;
        xT[(j * 4 + 2) * 129 + tn] = x[j].z;
        xT[(j * 4 + 3) * 129 + tn] = x[j].w;
      }
    }
    __syncthreads();
#pragma unroll 8
    for (int n = 0; n < 128; ++n) {
      const float2 aw = *reinterpret_cast<const float2*>(&awr[(kk0 >> 1) * 512 + (128 + n) * 2]);
      const float xv = xT[dd * 129 + n];
      Y0 += aw.x * xv; Y1 += aw.y * xv;
    }
    __syncthreads();
  }
  float* dst = part + (size_t)blockIdx.x * REC;
  dst[kk0 * 64 + dd] = Y0;
  dst[(kk0 + 1) * 64 + dd] = Y1;
  if (tid < 16) dst[512 + tid] = accST[tid];
}

// Per (b,kk): reduce partials -> updates -> GRU -> LN -> MLP -> new slots
__global__ __launch_bounds__(64) void gru_mlp(
    const float* __restrict__ part, const float* __restrict__ slots_in,
    const float* __restrict__ lniw, const float* __restrict__ lnib,
    const float* __restrict__ wv, const float* __restrict__ bv,
    const float* __restrict__ wih, const float* __restrict__ bih,
    const float* __restrict__ whh, const float* __restrict__ bhh,
    const float* __restrict__ lnfw, const float* __restrict__ lnfb,
    const float* __restrict__ w1, const float* __restrict__ b1,
    const float* __restrict__ w2, const float* __restrict__ b2,
    float* __restrict__ slots_out) {
  const int bk_i = blockIdx.x;            // b*8+kk
  const int b = bk_i >> 3, kk = bk_i & 7;
  const int d = threadIdx.x;
  __shared__ float xs[64], ush[64], psh[64], hsh[64], hid[128];
  float Y = 0.f, S = 0.f, T1 = 0.f;
  for (int ch = 0; ch < 16; ++ch) {
    const float* p = part + (size_t)(b * 16 + ch) * REC;
    Y += p[kk * 64 + d];
    S += p[512 + kk];
    T1 += p[520 + kk];
  }
  // xsum[c] = ln_in_w*(Y - t1) + ln_in_b*S ; updates = wv^T xsum + S*bv
  xs[d] = lniw[d] * (Y - T1) + lnib[d] * S;
  const float prev = slots_in[bk_i * 64 + d];
  psh[d] = prev;
  __syncthreads();
  float u = S * bv[d];
  for (int c = 0; c < 64; ++c) u += wv[c * 64 + d] * xs[c];
  ush[d] = u;
  __syncthreads();
  float g0 = bih[d], g1 = bih[64 + d], g2 = bih[128 + d];
  float h0 = bhh[d], h1 = bhh[64 + d], h2 = bhh[128 + d];
  for (int c = 0; c < 64; ++c) {
    const float uc = ush[c], pc = psh[c];
    g0 += uc * wih[c * 192 + d];
    g1 += uc * wih[c * 192 + 64 + d];
    g2 += uc * wih[c * 192 + 128 + d];
    h0 += pc * whh[c * 192 + d];
    h1 += pc * whh[c * 192 + 64 + d];
    h2 += pc * whh[c * 192 + 128 + d];
  }
  const float r = 1.f / (1.f + expf(-(g0 + h0)));
  const float z = 1.f / (1.f + expf(-(g1 + h1)));
  const float nn = tanhf(g2 + r * h2);
  const float sn = (1.f - z) * nn + z * prev;
  const float m = wsum64(sn) * (1.f / 64.f);
  const float df = sn - m;
  const float var = wsum64(df * df) * (1.f / 64.f);
  const float rr = 1.f / sqrtf(var + LN_EPS);
  const float h = df * rr * lnfw[d] + lnfb[d];
  hsh[d] = h;
  __syncthreads();
  float a0 = b1[d], a1 = b1[64 + d];
  for (int c = 0; c < 64; ++c) {
    const float hc = hsh[c];
    a0 += hc * w1[c * 128 + d];
    a1 += hc * w1[c * 128 + 64 + d];
  }
  hid[d] = fmaxf(a0, 0.f);
  hid[64 + d] = fmaxf(a1, 0.f);
  __syncthreads();
  float o = b2[d];
  for (int j = 0; j < 128; ++j) o += hid[j] * w2[j * 64 + d];
  slots_out[bk_i * 64 + d] = sn + o;
}

extern "C" void kernel_launch(void* const* d_in, const int* in_sizes, int n_in,
                              void* d_out, int out_size, void* d_ws, size_t ws_size,
                              hipStream_t stream) {
  const float* inp   = (const float*)d_in[0];
  const float* noise = (const float*)d_in[1];
  const float* mu    = (const float*)d_in[2];
  const float* sg    = (const float*)d_in[3];
  const float* lniw  = (const float*)d_in[4];
  const float* lnib  = (const float*)d_in[5];
  const float* lnsw  = (const float*)d_in[6];
  const float* lnsb  = (const float*)d_in[7];
  const float* lnfw  = (const float*)d_in[8];
  const float* lnfb  = (const float*)d_in[9];
  const float* wk    = (const float*)d_in[10];
  const float* bk    = (const float*)d_in[11];
  const float* wq    = (const float*)d_in[12];
  const float* bq    = (const float*)d_in[13];
  const float* wv    = (const float*)d_in[14];
  const float* bv    = (const float*)d_in[15];
  const float* wih   = (const float*)d_in[16];
  const float* bih   = (const float*)d_in[17];
  const float* whh   = (const float*)d_in[18];
  const float* bhh   = (const float*)d_in[19];
  const float* w1    = (const float*)d_in[20];
  const float* b1    = (const float*)d_in[21];
  const float* w2    = (const float*)d_in[22];
  const float* b2    = (const float*)d_in[23];
  float* ws = (float*)d_ws;
  float* slots = ws;                              // 32768
  float* qprep = ws + 32768;                      // 64*528 = 33792
  float* part  = ws + 32768 + 64 * REC;           // 1024*528 = 540672
  float* out   = (float*)d_out;
  init_slots<<<64, 512, 0, stream>>>(noise, mu, sg, slots);
  for (int it = 0; it < 3; ++it) {
    prep_q<<<B_ * K_, 64, 0, stream>>>(slots, lnsw, lnsb, wq, bq, wk, bk, lniw, lnib, qprep);
    attn_pass<<<B_ * CHUNKS, 256, 0, stream>>>(inp, qprep, part);
    gru_mlp<<<B_ * K_, 64, 0, stream>>>(part, slots, lniw, lnib, wv, bv, wih, bih, whh, bhh,
                                        lnfw, lnfb, w1, b1, w2, b2, (it == 2) ? out : slots);
  }
}